// Round 1
// baseline (1784.732 us; speedup 1.0000x reference)
//
#include <hip/hip_runtime.h>
#include <stdint.h>

namespace {

constexpr float EPSF = 1e-5f;
constexpr float QK_SCALE = 0.17677669529663687f;  // 32^-0.5

__device__ __forceinline__ float lo16(uint32_t u) { return __uint_as_float(u << 16); }
__device__ __forceinline__ float hi16(uint32_t u) { return __uint_as_float(u & 0xFFFF0000u); }
__device__ __forceinline__ uint16_t f2bf(float f) {  // RNE float->bf16
  uint32_t u = __float_as_uint(f);
  return (uint16_t)((u + 0x7FFFu + ((u >> 16) & 1u)) >> 16);
}
__device__ __forceinline__ float clip1(float v) { return fminf(fmaxf(v, -1.f), 1.f); }

// ---------------- K0: fold BN into transposed weights ----------------
// wqkvt[c][d] (128x512), wpt[c2][d] (256x128), w1t[c][d] (128x256), w2t[c2][d] (256x128)
__global__ void k0_fold(
    const float* __restrict__ Wq, const float* __restrict__ gq, const float* __restrict__ bq,
    const float* __restrict__ mq, const float* __restrict__ vq,
    const float* __restrict__ Wp, const float* __restrict__ gp, const float* __restrict__ bp,
    const float* __restrict__ mp, const float* __restrict__ vp,
    const float* __restrict__ W1, const float* __restrict__ g1, const float* __restrict__ b1,
    const float* __restrict__ m1, const float* __restrict__ v1,
    const float* __restrict__ W2, const float* __restrict__ g2, const float* __restrict__ b2,
    const float* __restrict__ m2, const float* __restrict__ v2,
    float* __restrict__ wqkvt, float* __restrict__ shq,
    float* __restrict__ wpt, float* __restrict__ shp,
    float* __restrict__ w1t, float* __restrict__ sh1,
    float* __restrict__ w2t, float* __restrict__ sh2) {
  int id = blockIdx.x * 256 + threadIdx.x;
  if (id < 65536) {
    int c = id >> 9, d = id & 511;
    wqkvt[id] = Wq[d * 128 + c] * (gq[d] * rsqrtf(vq[d] + EPSF));
  } else if (id < 98304) {
    int j = id - 65536; int d = j & 127, c2 = j >> 7;
    wpt[j] = Wp[d * 256 + c2] * (gp[d] * rsqrtf(vp[d] + EPSF));
  } else if (id < 131072) {
    int j = id - 98304; int d = j & 255, c = j >> 8;
    w1t[j] = W1[d * 128 + c] * (g1[d] * rsqrtf(v1[d] + EPSF));
  } else if (id < 163840) {
    int j = id - 131072; int d = j & 127, c2 = j >> 7;
    w2t[j] = W2[d * 256 + c2] * (g2[d] * rsqrtf(v2[d] + EPSF));
  } else if (id < 164864) {
    int j = id - 163840;
    if (j < 512)      shq[j] = bq[j] - mq[j] * (gq[j] * rsqrtf(vq[j] + EPSF));
    else if (j < 640) { int d = j - 512; shp[d] = bp[d] - mp[d] * (gp[d] * rsqrtf(vp[d] + EPSF)); }
    else if (j < 896) { int d = j - 640; sh1[d] = b1[d] - m1[d] * (g1[d] * rsqrtf(v1[d] + EPSF)); }
    else              { int d = j - 896; sh2[d] = b2[d] - m2[d] * (g2[d] * rsqrtf(v2[d] + EPSF)); }
  }
}

// ---------------- K1: qkv = BN(x_in @ Wqkv^T) -> q,k,v bf16 ----------------
// x: [B][128][1024] (channel-major); qkv split per head: q/k [b][h][n][32], v [b][h][n][64]
__global__ __launch_bounds__(256) void k1_qkv(
    const float* __restrict__ x, const float* __restrict__ wt, const float* __restrict__ sh,
    uint16_t* __restrict__ qws, uint16_t* __restrict__ kws, uint16_t* __restrict__ vws) {
  __shared__ float xs[128][32];
  const int t = threadIdx.x;
  const int b = blockIdx.x >> 5, n0 = (blockIdx.x & 31) << 5;
  const float* xp = x + (size_t)b * (128 * 1024) + n0;
  {
    const int j = (t & 7) << 2;
    #pragma unroll
    for (int it = 0; it < 4; ++it) {
      const int c = (t >> 3) + (it << 5);
      *(float4*)&xs[c][j] = *(const float4*)(xp + c * 1024 + j);
    }
  }
  __syncthreads();
  const int d0 = (t & 63) << 3, j0 = (t >> 6) << 3;
  float acc[8][8];
  #pragma unroll
  for (int a = 0; a < 8; ++a)
    #pragma unroll
    for (int bb = 0; bb < 8; ++bb) acc[a][bb] = 0.f;
  for (int c = 0; c < 128; ++c) {
    const float4 xa = *(const float4*)&xs[c][j0];
    const float4 xb = *(const float4*)&xs[c][j0 + 4];
    const float4 wa = *(const float4*)(wt + c * 512 + d0);
    const float4 wb = *(const float4*)(wt + c * 512 + d0 + 4);
    const float xr[8] = {xa.x, xa.y, xa.z, xa.w, xb.x, xb.y, xb.z, xb.w};
    const float wr[8] = {wa.x, wa.y, wa.z, wa.w, wb.x, wb.y, wb.z, wb.w};
    #pragma unroll
    for (int dd = 0; dd < 8; ++dd)
      #pragma unroll
      for (int jj = 0; jj < 8; ++jj)
        acc[dd][jj] = fmaf(wr[dd], xr[jj], acc[dd][jj]);
  }
  float shr[8];
  #pragma unroll
  for (int dd = 0; dd < 8; ++dd) shr[dd] = sh[d0 + dd];
  const int h = d0 >> 7, r = d0 & 127;
  uint16_t* dst; int stride;
  if (r < 32)      { dst = qws + ((size_t)(b * 4 + h) * 1024 + n0 + j0) * 32 + r;        stride = 32; }
  else if (r < 64) { dst = kws + ((size_t)(b * 4 + h) * 1024 + n0 + j0) * 32 + (r - 32); stride = 32; }
  else             { dst = vws + ((size_t)(b * 4 + h) * 1024 + n0 + j0) * 64 + (r - 64); stride = 64; }
  #pragma unroll
  for (int jj = 0; jj < 8; ++jj) {
    uint32_t p0 = (uint32_t)f2bf(acc[0][jj] + shr[0]) | ((uint32_t)f2bf(acc[1][jj] + shr[1]) << 16);
    uint32_t p1 = (uint32_t)f2bf(acc[2][jj] + shr[2]) | ((uint32_t)f2bf(acc[3][jj] + shr[3]) << 16);
    uint32_t p2 = (uint32_t)f2bf(acc[4][jj] + shr[4]) | ((uint32_t)f2bf(acc[5][jj] + shr[5]) << 16);
    uint32_t p3 = (uint32_t)f2bf(acc[6][jj] + shr[6]) | ((uint32_t)f2bf(acc[7][jj] + shr[7]) << 16);
    *(uint4*)(dst + (size_t)jj * stride) = make_uint4(p0, p1, p2, p3);
  }
}

// ---------------- K2: attention (fp32 vector), one block per (b,h,16-query tile) ----------------
__global__ __launch_bounds__(256) void k2_attn(
    const uint16_t* __restrict__ qws, const uint16_t* __restrict__ kws,
    const uint16_t* __restrict__ vws, const float* __restrict__ ab,
    float* __restrict__ ows) {
  __shared__ float S[16][1025];
  __shared__ float biasr[1024];
  __shared__ float rinv[16];
  const int t = threadIdx.x;
  const int blk = blockIdx.x;
  const int qt = blk & 63, h = (blk >> 6) & 3, b = blk >> 8;
  const int n0 = qt << 4;
  for (int i = t; i < 1024; i += 256) biasr[i] = ab[(h << 10) + i];
  __syncthreads();
  const size_t bh = (size_t)(b * 4 + h);
  // ---- QK^T * scale + bias ----
  {
    const int q = t & 15, mg = t >> 4;
    const int nq = n0 + q;
    const uint4* qp = (const uint4*)(qws + (bh * 1024 + nq) * 32);
    uint4 qa = qp[0], qb = qp[1], qc = qp[2], qd = qp[3];
    float Q[32];
    {
      const uint4 uu[4] = {qa, qb, qc, qd};
      #pragma unroll
      for (int wdi = 0; wdi < 4; ++wdi) {
        Q[wdi * 8 + 0] = lo16(uu[wdi].x); Q[wdi * 8 + 1] = hi16(uu[wdi].x);
        Q[wdi * 8 + 2] = lo16(uu[wdi].y); Q[wdi * 8 + 3] = hi16(uu[wdi].y);
        Q[wdi * 8 + 4] = lo16(uu[wdi].z); Q[wdi * 8 + 5] = hi16(uu[wdi].z);
        Q[wdi * 8 + 6] = lo16(uu[wdi].w); Q[wdi * 8 + 7] = hi16(uu[wdi].w);
      }
    }
    const int qrow = nq >> 5, qcol = nq & 31;
    const uint16_t* kbase = kws + bh * (1024 * 32);
    for (int i = 0; i < 64; ++i) {
      const int m = (mg << 6) + i;
      const uint4* kp = (const uint4*)(kbase + (m << 5));
      float s = 0.f;
      #pragma unroll
      for (int wdi = 0; wdi < 4; ++wdi) {
        const uint4 u = kp[wdi];
        s = fmaf(lo16(u.x), Q[wdi * 8 + 0], s); s = fmaf(hi16(u.x), Q[wdi * 8 + 1], s);
        s = fmaf(lo16(u.y), Q[wdi * 8 + 2], s); s = fmaf(hi16(u.y), Q[wdi * 8 + 3], s);
        s = fmaf(lo16(u.z), Q[wdi * 8 + 4], s); s = fmaf(hi16(u.z), Q[wdi * 8 + 5], s);
        s = fmaf(lo16(u.w), Q[wdi * 8 + 6], s); s = fmaf(hi16(u.w), Q[wdi * 8 + 7], s);
      }
      int dr = qrow - (m >> 5); dr = dr < 0 ? -dr : dr;
      int dc = qcol - (m & 31); dc = dc < 0 ? -dc : dc;
      S[q][m] = fmaf(s, QK_SCALE, biasr[(dr << 5) + dc]);
    }
  }
  __syncthreads();
  // ---- row softmax (wave per 4 rows) ----
  {
    const int w = t >> 6, l = t & 63;
    #pragma unroll
    for (int rr = 0; rr < 4; ++rr) {
      const int qq = (w << 2) + rr;
      float vals[16]; float mx = -3.4e38f;
      #pragma unroll
      for (int j = 0; j < 16; ++j) { vals[j] = S[qq][(j << 6) + l]; mx = fmaxf(mx, vals[j]); }
      #pragma unroll
      for (int off = 32; off > 0; off >>= 1) mx = fmaxf(mx, __shfl_xor(mx, off, 64));
      float sum = 0.f;
      #pragma unroll
      for (int j = 0; j < 16; ++j) { float e = __expf(vals[j] - mx); S[qq][(j << 6) + l] = e; sum += e; }
      #pragma unroll
      for (int off = 32; off > 0; off >>= 1) sum += __shfl_xor(sum, off, 64);
      if (l == 0) rinv[qq] = 1.f / sum;
    }
  }
  __syncthreads();
  // ---- P @ V ----
  {
    const int q2 = t >> 4, d0 = (t & 15) << 2;
    const uint16_t* vb = vws + bh * (1024 * 64) + d0;
    float a0 = 0.f, a1 = 0.f, a2 = 0.f, a3 = 0.f;
    #pragma unroll 4
    for (int m = 0; m < 1024; ++m) {
      const float p = S[q2][m];
      const uint2 vv = *(const uint2*)(vb + (m << 6));
      a0 = fmaf(p, lo16(vv.x), a0);
      a1 = fmaf(p, hi16(vv.x), a1);
      a2 = fmaf(p, lo16(vv.y), a2);
      a3 = fmaf(p, hi16(vv.y), a3);
    }
    const float inv = rinv[q2];
    *(float4*)(ows + ((size_t)b * 1024 + n0 + q2) * 256 + (h << 6) + d0) =
        make_float4(a0 * inv, a1 * inv, a2 * inv, a3 * inv);
  }
}

// ---------------- K3: x1 = x_in + BN(hardtanh(o) @ Wproj^T) ----------------
__global__ __launch_bounds__(256) void k3_proj(
    const float* __restrict__ ows, const float* __restrict__ x,
    const float* __restrict__ wt, const float* __restrict__ sh,
    float* __restrict__ x1) {
  __shared__ float os[256][36];
  const int t = threadIdx.x;
  const int b = blockIdx.x >> 5, n0 = (blockIdx.x & 31) << 5;
  {
    const int c0 = (t & 63) << 2;
    #pragma unroll
    for (int it = 0; it < 8; ++it) {
      const int j = (t >> 6) + (it << 2);
      float4 v4 = *(const float4*)(ows + ((size_t)b * 1024 + n0 + j) * 256 + c0);
      os[c0][j] = clip1(v4.x); os[c0 + 1][j] = clip1(v4.y);
      os[c0 + 2][j] = clip1(v4.z); os[c0 + 3][j] = clip1(v4.w);
    }
  }
  __syncthreads();
  const int d0 = (t & 31) << 2, j0 = (t >> 5) << 2;
  float acc[4][4];
  #pragma unroll
  for (int a = 0; a < 4; ++a)
    #pragma unroll
    for (int bb = 0; bb < 4; ++bb) acc[a][bb] = 0.f;
  for (int c2 = 0; c2 < 256; ++c2) {
    const float4 ov = *(const float4*)&os[c2][j0];
    const float4 wv = *(const float4*)(wt + c2 * 128 + d0);
    const float o_[4] = {ov.x, ov.y, ov.z, ov.w};
    const float w_[4] = {wv.x, wv.y, wv.z, wv.w};
    #pragma unroll
    for (int dd = 0; dd < 4; ++dd)
      #pragma unroll
      for (int jj = 0; jj < 4; ++jj)
        acc[dd][jj] = fmaf(w_[dd], o_[jj], acc[dd][jj]);
  }
  float res[4][4];
  #pragma unroll
  for (int dd = 0; dd < 4; ++dd) {
    const float shv = sh[d0 + dd];
    const float4 xv = *(const float4*)(x + ((size_t)b * 128 + d0 + dd) * 1024 + n0 + j0);
    res[dd][0] = acc[dd][0] + shv + xv.x;
    res[dd][1] = acc[dd][1] + shv + xv.y;
    res[dd][2] = acc[dd][2] + shv + xv.z;
    res[dd][3] = acc[dd][3] + shv + xv.w;
  }
  #pragma unroll
  for (int jj = 0; jj < 4; ++jj) {
    *(float4*)(x1 + ((size_t)b * 1024 + n0 + j0 + jj) * 128 + d0) =
        make_float4(res[0][jj], res[1][jj], res[2][jj], res[3][jj]);
  }
}

// ---------------- K4: h1 = hardtanh(BN(x1 @ Wf1^T)) -> bf16 ----------------
__global__ __launch_bounds__(256) void k4_f1(
    const float* __restrict__ x1, const float* __restrict__ wt, const float* __restrict__ sh,
    uint16_t* __restrict__ h1) {
  __shared__ float xs[128][36];
  const int t = threadIdx.x;
  const int b = blockIdx.x >> 5, n0 = (blockIdx.x & 31) << 5;
  {
    const int c0 = (t & 31) << 2;
    #pragma unroll
    for (int it = 0; it < 4; ++it) {
      const int j = (t >> 5) + (it << 3);
      float4 v4 = *(const float4*)(x1 + ((size_t)b * 1024 + n0 + j) * 128 + c0);
      xs[c0][j] = v4.x; xs[c0 + 1][j] = v4.y; xs[c0 + 2][j] = v4.z; xs[c0 + 3][j] = v4.w;
    }
  }
  __syncthreads();
  const int d0 = (t & 63) << 2, j0 = (t >> 6) << 3;
  float acc[4][8];
  #pragma unroll
  for (int a = 0; a < 4; ++a)
    #pragma unroll
    for (int bb = 0; bb < 8; ++bb) acc[a][bb] = 0.f;
  for (int c = 0; c < 128; ++c) {
    const float4 xa = *(const float4*)&xs[c][j0];
    const float4 xb = *(const float4*)&xs[c][j0 + 4];
    const float4 wv = *(const float4*)(wt + c * 256 + d0);
    const float xr[8] = {xa.x, xa.y, xa.z, xa.w, xb.x, xb.y, xb.z, xb.w};
    const float w_[4] = {wv.x, wv.y, wv.z, wv.w};
    #pragma unroll
    for (int dd = 0; dd < 4; ++dd)
      #pragma unroll
      for (int jj = 0; jj < 8; ++jj)
        acc[dd][jj] = fmaf(w_[dd], xr[jj], acc[dd][jj]);
  }
  float shr[4];
  #pragma unroll
  for (int dd = 0; dd < 4; ++dd) shr[dd] = sh[d0 + dd];
  #pragma unroll
  for (int jj = 0; jj < 8; ++jj) {
    const int n = n0 + j0 + jj;
    const float v0 = clip1(acc[0][jj] + shr[0]);
    const float v1 = clip1(acc[1][jj] + shr[1]);
    const float v2 = clip1(acc[2][jj] + shr[2]);
    const float v3 = clip1(acc[3][jj] + shr[3]);
    uint32_t p0 = (uint32_t)f2bf(v0) | ((uint32_t)f2bf(v1) << 16);
    uint32_t p1 = (uint32_t)f2bf(v2) | ((uint32_t)f2bf(v3) << 16);
    *(uint2*)(h1 + ((size_t)b * 1024 + n) * 256 + d0) = make_uint2(p0, p1);
  }
}

// ---------------- K5: out[b][c][n] = x1 + BN(h1 @ Wf2^T) ----------------
__global__ __launch_bounds__(256) void k5_f2(
    const uint16_t* __restrict__ h1, const float* __restrict__ x1,
    const float* __restrict__ wt, const float* __restrict__ sh,
    float* __restrict__ out) {
  __shared__ float hs[256][36];
  const int t = threadIdx.x;
  const int b = blockIdx.x >> 5, n0 = (blockIdx.x & 31) << 5;
  {
    const int c0 = (t & 31) << 3;
    #pragma unroll
    for (int it = 0; it < 4; ++it) {
      const int j = (t >> 5) + (it << 3);
      uint4 u = *(const uint4*)(h1 + ((size_t)b * 1024 + n0 + j) * 256 + c0);
      hs[c0][j] = lo16(u.x); hs[c0 + 1][j] = hi16(u.x);
      hs[c0 + 2][j] = lo16(u.y); hs[c0 + 3][j] = hi16(u.y);
      hs[c0 + 4][j] = lo16(u.z); hs[c0 + 5][j] = hi16(u.z);
      hs[c0 + 6][j] = lo16(u.w); hs[c0 + 7][j] = hi16(u.w);
    }
  }
  __syncthreads();
  const int d0 = (t & 31) << 2, j0 = (t >> 5) << 2;
  float acc[4][4];
  #pragma unroll
  for (int a = 0; a < 4; ++a)
    #pragma unroll
    for (int bb = 0; bb < 4; ++bb) acc[a][bb] = 0.f;
  for (int c2 = 0; c2 < 256; ++c2) {
    const float4 hv = *(const float4*)&hs[c2][j0];
    const float4 wv = *(const float4*)(wt + c2 * 128 + d0);
    const float h_[4] = {hv.x, hv.y, hv.z, hv.w};
    const float w_[4] = {wv.x, wv.y, wv.z, wv.w};
    #pragma unroll
    for (int dd = 0; dd < 4; ++dd)
      #pragma unroll
      for (int jj = 0; jj < 4; ++jj)
        acc[dd][jj] = fmaf(w_[dd], h_[jj], acc[dd][jj]);
  }
  float shr[4];
  #pragma unroll
  for (int dd = 0; dd < 4; ++dd) shr[dd] = sh[d0 + dd];
  float res[4][4];
  #pragma unroll
  for (int jj = 0; jj < 4; ++jj) {
    const float4 xv = *(const float4*)(x1 + ((size_t)b * 1024 + n0 + j0 + jj) * 128 + d0);
    res[0][jj] = acc[0][jj] + shr[0] + xv.x;
    res[1][jj] = acc[1][jj] + shr[1] + xv.y;
    res[2][jj] = acc[2][jj] + shr[2] + xv.z;
    res[3][jj] = acc[3][jj] + shr[3] + xv.w;
  }
  #pragma unroll
  for (int dd = 0; dd < 4; ++dd) {
    *(float4*)(out + ((size_t)b * 128 + d0 + dd) * 1024 + n0 + j0) =
        make_float4(res[dd][0], res[dd][1], res[dd][2], res[dd][3]);
  }
}

}  // namespace

extern "C" void kernel_launch(void* const* d_in, const int* in_sizes, int n_in,
                              void* d_out, int out_size, void* d_ws, size_t ws_size,
                              hipStream_t stream) {
  const float* x  = (const float*)d_in[0];
  const float* Wq = (const float*)d_in[1];
  const float* gq = (const float*)d_in[2];
  const float* bq = (const float*)d_in[3];
  const float* mq = (const float*)d_in[4];
  const float* vq = (const float*)d_in[5];
  const float* Wp = (const float*)d_in[6];
  const float* gp = (const float*)d_in[7];
  const float* bp = (const float*)d_in[8];
  const float* mp = (const float*)d_in[9];
  const float* vp = (const float*)d_in[10];
  const float* W1 = (const float*)d_in[11];
  const float* g1 = (const float*)d_in[12];
  const float* b1 = (const float*)d_in[13];
  const float* m1 = (const float*)d_in[14];
  const float* v1 = (const float*)d_in[15];
  const float* W2 = (const float*)d_in[16];
  const float* g2 = (const float*)d_in[17];
  const float* b2 = (const float*)d_in[18];
  const float* m2 = (const float*)d_in[19];
  const float* v2 = (const float*)d_in[20];
  const float* ab = (const float*)d_in[21];
  // d_in[22] (bias_idxs) unused: index computed on the fly.
  float* out = (float*)d_out;

  char* ws = (char*)d_ws;
  uint16_t* qws = (uint16_t*)(ws);                 // 8 MiB
  uint16_t* kws = (uint16_t*)(ws + (8ull << 20));  // 8 MiB
  uint16_t* vws = (uint16_t*)(ws + (16ull << 20)); // 16 MiB
  float*    ows = (float*)(ws + (32ull << 20));    // 32 MiB
  float*    x1  = (float*)(ws + (64ull << 20));    // 16 MiB
  uint16_t* h1  = (uint16_t*)(ws);                 // reuse q/k region (dead after K2)
  float* wqkvt = (float*)(ws + (80ull << 20));
  float* shq   = wqkvt + 65536;
  float* wpt   = shq + 512;
  float* shp   = wpt + 32768;
  float* w1t   = shp + 128;
  float* sh1   = w1t + 32768;
  float* w2t   = sh1 + 256;
  float* sh2   = w2t + 32768;

  k0_fold<<<644, 256, 0, stream>>>(Wq, gq, bq, mq, vq, Wp, gp, bp, mp, vp,
                                   W1, g1, b1, m1, v1, W2, g2, b2, m2, v2,
                                   wqkvt, shq, wpt, shp, w1t, sh1, w2t, sh2);
  k1_qkv<<<1024, 256, 0, stream>>>(x, wqkvt, shq, qws, kws, vws);
  k2_attn<<<8192, 256, 0, stream>>>(qws, kws, vws, ab, ows);
  k3_proj<<<1024, 256, 0, stream>>>(ows, x, wpt, shp, x1);
  k4_f1<<<1024, 256, 0, stream>>>(x1, w1t, sh1, h1);
  k5_f2<<<1024, 256, 0, stream>>>(h1, x1, w2t, sh2, out);
  (void)in_sizes; (void)n_in; (void)out_size; (void)ws_size;
}

// Round 2
// 359.628 us; speedup vs baseline: 4.9627x; 4.9627x over previous
//
#include <hip/hip_runtime.h>
#include <stdint.h>

namespace {

constexpr float EPSF = 1e-5f;
constexpr float QK_SCALE = 0.17677669529663687f;  // 32^-0.5

typedef __attribute__((ext_vector_type(8))) short short8;
typedef __attribute__((ext_vector_type(4))) float f32x4;

__device__ __forceinline__ float lo16(uint32_t u) { return __uint_as_float(u << 16); }
__device__ __forceinline__ float hi16(uint32_t u) { return __uint_as_float(u & 0xFFFF0000u); }
__device__ __forceinline__ uint16_t f2bf(float f) {  // RNE float->bf16
  uint32_t u = __float_as_uint(f);
  return (uint16_t)((u + 0x7FFFu + ((u >> 16) & 1u)) >> 16);
}
__device__ __forceinline__ uint32_t pk2(float a, float b) {
  return (uint32_t)f2bf(a) | ((uint32_t)f2bf(b) << 16);
}
__device__ __forceinline__ float clip1(float v) { return fminf(fmaxf(v, -1.f), 1.f); }

// ---------------- K0: fold BN into transposed weights ----------------
__global__ void k0_fold(
    const float* __restrict__ Wq, const float* __restrict__ gq, const float* __restrict__ bq,
    const float* __restrict__ mq, const float* __restrict__ vq,
    const float* __restrict__ Wp, const float* __restrict__ gp, const float* __restrict__ bp,
    const float* __restrict__ mp, const float* __restrict__ vp,
    const float* __restrict__ W1, const float* __restrict__ g1, const float* __restrict__ b1,
    const float* __restrict__ m1, const float* __restrict__ v1,
    const float* __restrict__ W2, const float* __restrict__ g2, const float* __restrict__ b2,
    const float* __restrict__ m2, const float* __restrict__ v2,
    float* __restrict__ wqkvt, float* __restrict__ shq,
    float* __restrict__ wpt, float* __restrict__ shp,
    float* __restrict__ w1t, float* __restrict__ sh1,
    float* __restrict__ w2t, float* __restrict__ sh2) {
  int id = blockIdx.x * 256 + threadIdx.x;
  if (id < 65536) {
    int c = id >> 9, d = id & 511;
    wqkvt[id] = Wq[d * 128 + c] * (gq[d] * rsqrtf(vq[d] + EPSF));
  } else if (id < 98304) {
    int j = id - 65536; int d = j & 127, c2 = j >> 7;
    wpt[j] = Wp[d * 256 + c2] * (gp[d] * rsqrtf(vp[d] + EPSF));
  } else if (id < 131072) {
    int j = id - 98304; int d = j & 255, c = j >> 8;
    w1t[j] = W1[d * 128 + c] * (g1[d] * rsqrtf(v1[d] + EPSF));
  } else if (id < 163840) {
    int j = id - 131072; int d = j & 127, c2 = j >> 7;
    w2t[j] = W2[d * 256 + c2] * (g2[d] * rsqrtf(v2[d] + EPSF));
  } else if (id < 164864) {
    int j = id - 163840;
    if (j < 512)      shq[j] = bq[j] - mq[j] * (gq[j] * rsqrtf(vq[j] + EPSF));
    else if (j < 640) { int d = j - 512; shp[d] = bp[d] - mp[d] * (gp[d] * rsqrtf(vp[d] + EPSF)); }
    else if (j < 896) { int d = j - 640; sh1[d] = b1[d] - m1[d] * (g1[d] * rsqrtf(v1[d] + EPSF)); }
    else              { int d = j - 896; sh2[d] = b2[d] - m2[d] * (g2[d] * rsqrtf(v2[d] + EPSF)); }
  }
}

// ---------------- K1: qkv = BN(x_in @ Wqkv^T) -> qt (T), k (row-major), vt (T), bf16 ----------------
// qt: [bh][32 dims][1024 n]; kws: [bh][1024 n][32 dims]; vt: [bh][64 dims][1024 n]
__global__ __launch_bounds__(256) void k1_qkv(
    const float* __restrict__ x, const float* __restrict__ wt, const float* __restrict__ sh,
    uint16_t* __restrict__ qt, uint16_t* __restrict__ kws, uint16_t* __restrict__ vt) {
  __shared__ float xs[128][32];
  const int t = threadIdx.x;
  const int b = blockIdx.x >> 5, n0 = (blockIdx.x & 31) << 5;
  const float* xp = x + (size_t)b * (128 * 1024) + n0;
  {
    const int j = (t & 7) << 2;
    #pragma unroll
    for (int it = 0; it < 4; ++it) {
      const int c = (t >> 3) + (it << 5);
      *(float4*)&xs[c][j] = *(const float4*)(xp + c * 1024 + j);
    }
  }
  __syncthreads();
  const int d0 = (t & 63) << 3, j0 = (t >> 6) << 3;
  float acc[8][8];
  #pragma unroll
  for (int a = 0; a < 8; ++a)
    #pragma unroll
    for (int bb = 0; bb < 8; ++bb) acc[a][bb] = 0.f;
  for (int c = 0; c < 128; ++c) {
    const float4 xa = *(const float4*)&xs[c][j0];
    const float4 xb = *(const float4*)&xs[c][j0 + 4];
    const float4 wa = *(const float4*)(wt + c * 512 + d0);
    const float4 wb = *(const float4*)(wt + c * 512 + d0 + 4);
    const float xr[8] = {xa.x, xa.y, xa.z, xa.w, xb.x, xb.y, xb.z, xb.w};
    const float wr[8] = {wa.x, wa.y, wa.z, wa.w, wb.x, wb.y, wb.z, wb.w};
    #pragma unroll
    for (int dd = 0; dd < 8; ++dd)
      #pragma unroll
      for (int jj = 0; jj < 8; ++jj)
        acc[dd][jj] = fmaf(wr[dd], xr[jj], acc[dd][jj]);
  }
  float shr[8];
  #pragma unroll
  for (int dd = 0; dd < 8; ++dd) shr[dd] = sh[d0 + dd];
  const int h = d0 >> 7, r = d0 & 127;
  const size_t bh = (size_t)(b * 4 + h);
  if (r < 32) {
    // transposed q: qt[bh][r+dd][n0+j0 .. +7]
    uint16_t* qp = qt + bh * (32 * 1024) + (size_t)r * 1024 + n0 + j0;
    #pragma unroll
    for (int dd = 0; dd < 8; ++dd) {
      const float s = shr[dd];
      uint4 u = make_uint4(pk2(acc[dd][0] + s, acc[dd][1] + s), pk2(acc[dd][2] + s, acc[dd][3] + s),
                           pk2(acc[dd][4] + s, acc[dd][5] + s), pk2(acc[dd][6] + s, acc[dd][7] + s));
      *(uint4*)(qp + (size_t)dd * 1024) = u;
    }
  } else if (r < 64) {
    // row-major k: kws[bh][n][r-32+dd]
    uint16_t* kp = kws + (bh * 1024 + n0 + j0) * 32 + (r - 32);
    #pragma unroll
    for (int jj = 0; jj < 8; ++jj) {
      uint4 u = make_uint4(pk2(acc[0][jj] + shr[0], acc[1][jj] + shr[1]),
                           pk2(acc[2][jj] + shr[2], acc[3][jj] + shr[3]),
                           pk2(acc[4][jj] + shr[4], acc[5][jj] + shr[5]),
                           pk2(acc[6][jj] + shr[6], acc[7][jj] + shr[7]));
      *(uint4*)(kp + (size_t)jj * 32) = u;
    }
  } else {
    // transposed v: vt[bh][r-64+dd][n0+j0 .. +7]
    uint16_t* vp = vt + bh * (64 * 1024) + (size_t)(r - 64) * 1024 + n0 + j0;
    #pragma unroll
    for (int dd = 0; dd < 8; ++dd) {
      const float s = shr[dd];
      uint4 u = make_uint4(pk2(acc[dd][0] + s, acc[dd][1] + s), pk2(acc[dd][2] + s, acc[dd][3] + s),
                           pk2(acc[dd][4] + s, acc[dd][5] + s), pk2(acc[dd][6] + s, acc[dd][7] + s));
      *(uint4*)(vp + (size_t)dd * 1024) = u;
    }
  }
}

// ---------------- K2: MFMA flash attention ----------------
// block = (b, h, 64 q-rows); 4 waves x 16 q each; online softmax over 32-key steps.
__global__ __launch_bounds__(256) void k2_attn(
    const uint16_t* __restrict__ qt, const uint16_t* __restrict__ kws,
    const uint16_t* __restrict__ vt, const float* __restrict__ ab,
    float* __restrict__ ows) {
  __shared__ float biasr[1024];
  __shared__ float osm[4][16][68];
  const int t = threadIdx.x;
  const int blk = blockIdx.x;
  const int qb = blk & 15, h = (blk >> 4) & 3, b = blk >> 6;
  for (int i = t; i < 1024; i += 256) biasr[i] = ab[(h << 10) + i];
  __syncthreads();
  const int w = t >> 6, l = t & 63;
  const int c = l & 15, g = l >> 4;
  const int nq = (qb << 6) + (w << 4) + c;  // this lane's q index (D col)
  const size_t bh = (size_t)(b * 4 + h);
  const uint16_t* qtb = qt + bh * (32 * 1024);
  const uint16_t* kbp = kws + bh * (1024 * 32);
  const uint16_t* vtb = vt + bh * (64 * 1024);
  // Q^T B-fragment: B[kdim=8g+j][q=c], once per wave
  short8 qf;
  #pragma unroll
  for (int j = 0; j < 8; ++j) qf[j] = (short)qtb[(size_t)((g << 3) + j) * 1024 + nq];
  const int qrow = nq >> 5, qcol = nq & 31;

  f32x4 o0 = {0.f, 0.f, 0.f, 0.f}, o1 = o0, o2 = o0, o3 = o0;
  float m_run = -1e30f, l_run = 0.f;

  union U { uint4 u; short8 s; };
  for (int kb = 0; kb < 1024; kb += 32) {
    // K A-fragments (coalesced): A[key=c][kdim=8g+j]
    U ka, kc;
    ka.u = *(const uint4*)(kbp + (size_t)(kb + c) * 32 + (g << 3));
    kc.u = *(const uint4*)(kbp + (size_t)(kb + 16 + c) * 32 + (g << 3));
    // V^T A-fragments (coalesced): A[d=16*dt+c][k=kb+8g+j] — issue early
    U v0, v1, v2, v3;
    v0.u = *(const uint4*)(vtb + (size_t)(0  + c) * 1024 + kb + (g << 3));
    v1.u = *(const uint4*)(vtb + (size_t)(16 + c) * 1024 + kb + (g << 3));
    v2.u = *(const uint4*)(vtb + (size_t)(32 + c) * 1024 + kb + (g << 3));
    v3.u = *(const uint4*)(vtb + (size_t)(48 + c) * 1024 + kb + (g << 3));

    const f32x4 z = {0.f, 0.f, 0.f, 0.f};
    f32x4 s0 = __builtin_amdgcn_mfma_f32_16x16x32_bf16(ka.s, qf, z, 0, 0, 0);
    f32x4 s1 = __builtin_amdgcn_mfma_f32_16x16x32_bf16(kc.s, qf, z, 0, 0, 0);

    // scale + bias; lane holds S[key = kb+4g+r (and +16)][q=nq]
    float p[8]; float mx = -1e30f;
    #pragma unroll
    for (int r = 0; r < 4; ++r) {
      const int key0 = kb + (g << 2) + r;
      int dr = qrow - (key0 >> 5); dr = dr < 0 ? -dr : dr;
      int dc = qcol - (key0 & 31); dc = dc < 0 ? -dc : dc;
      const float va = fmaf(s0[r], QK_SCALE, biasr[(dr << 5) + dc]);
      const int key1 = key0 + 16;
      int dr1 = qrow - (key1 >> 5); dr1 = dr1 < 0 ? -dr1 : dr1;
      int dc1 = qcol - (key1 & 31); dc1 = dc1 < 0 ? -dc1 : dc1;
      const float vb = fmaf(s1[r], QK_SCALE, biasr[(dr1 << 5) + dc1]);
      p[r] = va; p[4 + r] = vb;
      mx = fmaxf(mx, fmaxf(va, vb));
    }
    // row max across the 4 lane-groups (same q)
    mx = fmaxf(mx, __shfl_xor(mx, 16, 64));
    mx = fmaxf(mx, __shfl_xor(mx, 32, 64));
    const float m_new = fmaxf(m_run, mx);
    const float corr = __expf(m_run - m_new);
    m_run = m_new;
    float sum = 0.f;
    #pragma unroll
    for (int j = 0; j < 8; ++j) { p[j] = __expf(p[j] - m_new); sum += p[j]; }
    l_run = fmaf(l_run, corr, sum);
    #pragma unroll
    for (int i = 0; i < 4; ++i) { o0[i] *= corr; o1[i] *= corr; o2[i] *= corr; o3[i] *= corr; }

    // pack P to bf16 pairs; lane holds keys kb+4g+{0..3} (pa) and kb+16+4g+{0..3} (pb)
    const uint32_t pa0 = pk2(p[0], p[1]), pa1 = pk2(p[2], p[3]);
    const uint32_t pb0 = pk2(p[4], p[5]), pb1 = pk2(p[6], p[7]);
    // redistribute so lane holds keys kb+8g+{0..7} (P^T B-fragment)
    const uint32_t a0x16 = __shfl_xor(pa0, 16, 64), a1x16 = __shfl_xor(pa1, 16, 64);
    const uint32_t a0x32 = __shfl_xor(pa0, 32, 64), a1x32 = __shfl_xor(pa1, 32, 64);
    const uint32_t a0x48 = __shfl_xor(pa0, 48, 64), a1x48 = __shfl_xor(pa1, 48, 64);
    const uint32_t b0x16 = __shfl_xor(pb0, 16, 64), b1x16 = __shfl_xor(pb1, 16, 64);
    const uint32_t b0x32 = __shfl_xor(pb0, 32, 64), b1x32 = __shfl_xor(pb1, 32, 64);
    const uint32_t b0x48 = __shfl_xor(pb0, 48, 64), b1x48 = __shfl_xor(pb1, 48, 64);
    uint32_t t0, t1, t2, t3;
    if (g == 0)      { t0 = pa0;   t1 = pa1;   t2 = a0x16; t3 = a1x16; }
    else if (g == 1) { t0 = a0x48; t1 = a1x48; t2 = a0x32; t3 = a1x32; }
    else if (g == 2) { t0 = b0x32; t1 = b1x32; t2 = b0x48; t3 = b1x48; }
    else             { t0 = b0x16; t1 = b1x16; t2 = pb0;   t3 = pb1;   }
    U pf; pf.u = make_uint4(t0, t1, t2, t3);

    o0 = __builtin_amdgcn_mfma_f32_16x16x32_bf16(v0.s, pf.s, o0, 0, 0, 0);
    o1 = __builtin_amdgcn_mfma_f32_16x16x32_bf16(v1.s, pf.s, o1, 0, 0, 0);
    o2 = __builtin_amdgcn_mfma_f32_16x16x32_bf16(v2.s, pf.s, o2, 0, 0, 0);
    o3 = __builtin_amdgcn_mfma_f32_16x16x32_bf16(v3.s, pf.s, o3, 0, 0, 0);
  }

  float ls = l_run;
  ls += __shfl_xor(ls, 16, 64);
  ls += __shfl_xor(ls, 32, 64);
  const float inv = 1.f / ls;
  #pragma unroll
  for (int i = 0; i < 4; ++i) {
    osm[w][c][(g << 2) + i]      = o0[i] * inv;
    osm[w][c][16 + (g << 2) + i] = o1[i] * inv;
    osm[w][c][32 + (g << 2) + i] = o2[i] * inv;
    osm[w][c][48 + (g << 2) + i] = o3[i] * inv;
  }
  __syncthreads();
  const int q2 = l >> 2, dg = l & 3;
  const float4 r0 = *(const float4*)&osm[w][q2][dg * 16];
  const float4 r1 = *(const float4*)&osm[w][q2][dg * 16 + 4];
  const float4 r2 = *(const float4*)&osm[w][q2][dg * 16 + 8];
  const float4 r3 = *(const float4*)&osm[w][q2][dg * 16 + 12];
  float* op = ows + ((size_t)b * 1024 + (qb << 6) + (w << 4) + q2) * 256 + (h << 6) + dg * 16;
  *(float4*)(op)      = r0;
  *(float4*)(op + 4)  = r1;
  *(float4*)(op + 8)  = r2;
  *(float4*)(op + 12) = r3;
}

// ---------------- K3: x1 = x_in + BN(hardtanh(o) @ Wproj^T) ----------------
__global__ __launch_bounds__(256) void k3_proj(
    const float* __restrict__ ows, const float* __restrict__ x,
    const float* __restrict__ wt, const float* __restrict__ sh,
    float* __restrict__ x1) {
  __shared__ float os[256][36];
  const int t = threadIdx.x;
  const int b = blockIdx.x >> 5, n0 = (blockIdx.x & 31) << 5;
  {
    const int c0 = (t & 63) << 2;
    #pragma unroll
    for (int it = 0; it < 8; ++it) {
      const int j = (t >> 6) + (it << 2);
      float4 v4 = *(const float4*)(ows + ((size_t)b * 1024 + n0 + j) * 256 + c0);
      os[c0][j] = clip1(v4.x); os[c0 + 1][j] = clip1(v4.y);
      os[c0 + 2][j] = clip1(v4.z); os[c0 + 3][j] = clip1(v4.w);
    }
  }
  __syncthreads();
  const int d0 = (t & 31) << 2, j0 = (t >> 5) << 2;
  float acc[4][4];
  #pragma unroll
  for (int a = 0; a < 4; ++a)
    #pragma unroll
    for (int bb = 0; bb < 4; ++bb) acc[a][bb] = 0.f;
  for (int c2 = 0; c2 < 256; ++c2) {
    const float4 ov = *(const float4*)&os[c2][j0];
    const float4 wv = *(const float4*)(wt + c2 * 128 + d0);
    const float o_[4] = {ov.x, ov.y, ov.z, ov.w};
    const float w_[4] = {wv.x, wv.y, wv.z, wv.w};
    #pragma unroll
    for (int dd = 0; dd < 4; ++dd)
      #pragma unroll
      for (int jj = 0; jj < 4; ++jj)
        acc[dd][jj] = fmaf(w_[dd], o_[jj], acc[dd][jj]);
  }
  float res[4][4];
  #pragma unroll
  for (int dd = 0; dd < 4; ++dd) {
    const float shv = sh[d0 + dd];
    const float4 xv = *(const float4*)(x + ((size_t)b * 128 + d0 + dd) * 1024 + n0 + j0);
    res[dd][0] = acc[dd][0] + shv + xv.x;
    res[dd][1] = acc[dd][1] + shv + xv.y;
    res[dd][2] = acc[dd][2] + shv + xv.z;
    res[dd][3] = acc[dd][3] + shv + xv.w;
  }
  #pragma unroll
  for (int jj = 0; jj < 4; ++jj) {
    *(float4*)(x1 + ((size_t)b * 1024 + n0 + j0 + jj) * 128 + d0) =
        make_float4(res[0][jj], res[1][jj], res[2][jj], res[3][jj]);
  }
}

// ---------------- K4: h1 = hardtanh(BN(x1 @ Wf1^T)) -> bf16 ----------------
__global__ __launch_bounds__(256) void k4_f1(
    const float* __restrict__ x1, const float* __restrict__ wt, const float* __restrict__ sh,
    uint16_t* __restrict__ h1) {
  __shared__ float xs[128][36];
  const int t = threadIdx.x;
  const int b = blockIdx.x >> 5, n0 = (blockIdx.x & 31) << 5;
  {
    const int c0 = (t & 31) << 2;
    #pragma unroll
    for (int it = 0; it < 4; ++it) {
      const int j = (t >> 5) + (it << 3);
      float4 v4 = *(const float4*)(x1 + ((size_t)b * 1024 + n0 + j) * 128 + c0);
      xs[c0][j] = v4.x; xs[c0 + 1][j] = v4.y; xs[c0 + 2][j] = v4.z; xs[c0 + 3][j] = v4.w;
    }
  }
  __syncthreads();
  const int d0 = (t & 63) << 2, j0 = (t >> 6) << 3;
  float acc[4][8];
  #pragma unroll
  for (int a = 0; a < 4; ++a)
    #pragma unroll
    for (int bb = 0; bb < 8; ++bb) acc[a][bb] = 0.f;
  for (int c = 0; c < 128; ++c) {
    const float4 xa = *(const float4*)&xs[c][j0];
    const float4 xb = *(const float4*)&xs[c][j0 + 4];
    const float4 wv = *(const float4*)(wt + c * 256 + d0);
    const float xr[8] = {xa.x, xa.y, xa.z, xa.w, xb.x, xb.y, xb.z, xb.w};
    const float w_[4] = {wv.x, wv.y, wv.z, wv.w};
    #pragma unroll
    for (int dd = 0; dd < 4; ++dd)
      #pragma unroll
      for (int jj = 0; jj < 8; ++jj)
        acc[dd][jj] = fmaf(w_[dd], xr[jj], acc[dd][jj]);
  }
  float shr[4];
  #pragma unroll
  for (int dd = 0; dd < 4; ++dd) shr[dd] = sh[d0 + dd];
  #pragma unroll
  for (int jj = 0; jj < 8; ++jj) {
    const int n = n0 + j0 + jj;
    const float v0 = clip1(acc[0][jj] + shr[0]);
    const float v1 = clip1(acc[1][jj] + shr[1]);
    const float v2 = clip1(acc[2][jj] + shr[2]);
    const float v3 = clip1(acc[3][jj] + shr[3]);
    *(uint2*)(h1 + ((size_t)b * 1024 + n) * 256 + d0) = make_uint2(pk2(v0, v1), pk2(v2, v3));
  }
}

// ---------------- K5: out[b][c][n] = x1 + BN(h1 @ Wf2^T) ----------------
__global__ __launch_bounds__(256) void k5_f2(
    const uint16_t* __restrict__ h1, const float* __restrict__ x1,
    const float* __restrict__ wt, const float* __restrict__ sh,
    float* __restrict__ out) {
  __shared__ float hs[256][36];
  const int t = threadIdx.x;
  const int b = blockIdx.x >> 5, n0 = (blockIdx.x & 31) << 5;
  {
    const int c0 = (t & 31) << 3;
    #pragma unroll
    for (int it = 0; it < 4; ++it) {
      const int j = (t >> 5) + (it << 3);
      uint4 u = *(const uint4*)(h1 + ((size_t)b * 1024 + n0 + j) * 256 + c0);
      hs[c0][j] = lo16(u.x); hs[c0 + 1][j] = hi16(u.x);
      hs[c0 + 2][j] = lo16(u.y); hs[c0 + 3][j] = hi16(u.y);
      hs[c0 + 4][j] = lo16(u.z); hs[c0 + 5][j] = hi16(u.z);
      hs[c0 + 6][j] = lo16(u.w); hs[c0 + 7][j] = hi16(u.w);
    }
  }
  __syncthreads();
  const int d0 = (t & 31) << 2, j0 = (t >> 5) << 2;
  float acc[4][4];
  #pragma unroll
  for (int a = 0; a < 4; ++a)
    #pragma unroll
    for (int bb = 0; bb < 4; ++bb) acc[a][bb] = 0.f;
  for (int c2 = 0; c2 < 256; ++c2) {
    const float4 hv = *(const float4*)&hs[c2][j0];
    const float4 wv = *(const float4*)(wt + c2 * 128 + d0);
    const float h_[4] = {hv.x, hv.y, hv.z, hv.w};
    const float w_[4] = {wv.x, wv.y, wv.z, wv.w};
    #pragma unroll
    for (int dd = 0; dd < 4; ++dd)
      #pragma unroll
      for (int jj = 0; jj < 4; ++jj)
        acc[dd][jj] = fmaf(w_[dd], h_[jj], acc[dd][jj]);
  }
  float shr[4];
  #pragma unroll
  for (int dd = 0; dd < 4; ++dd) shr[dd] = sh[d0 + dd];
  float res[4][4];
  #pragma unroll
  for (int jj = 0; jj < 4; ++jj) {
    const float4 xv = *(const float4*)(x1 + ((size_t)b * 1024 + n0 + j0 + jj) * 128 + d0);
    res[0][jj] = acc[0][jj] + shr[0] + xv.x;
    res[1][jj] = acc[1][jj] + shr[1] + xv.y;
    res[2][jj] = acc[2][jj] + shr[2] + xv.z;
    res[3][jj] = acc[3][jj] + shr[3] + xv.w;
  }
  #pragma unroll
  for (int dd = 0; dd < 4; ++dd) {
    *(float4*)(out + ((size_t)b * 128 + d0 + dd) * 1024 + n0 + j0) =
        make_float4(res[dd][0], res[dd][1], res[dd][2], res[dd][3]);
  }
}

}  // namespace

extern "C" void kernel_launch(void* const* d_in, const int* in_sizes, int n_in,
                              void* d_out, int out_size, void* d_ws, size_t ws_size,
                              hipStream_t stream) {
  const float* x  = (const float*)d_in[0];
  const float* Wq = (const float*)d_in[1];
  const float* gq = (const float*)d_in[2];
  const float* bq = (const float*)d_in[3];
  const float* mq = (const float*)d_in[4];
  const float* vq = (const float*)d_in[5];
  const float* Wp = (const float*)d_in[6];
  const float* gp = (const float*)d_in[7];
  const float* bp = (const float*)d_in[8];
  const float* mp = (const float*)d_in[9];
  const float* vp = (const float*)d_in[10];
  const float* W1 = (const float*)d_in[11];
  const float* g1 = (const float*)d_in[12];
  const float* b1 = (const float*)d_in[13];
  const float* m1 = (const float*)d_in[14];
  const float* v1 = (const float*)d_in[15];
  const float* W2 = (const float*)d_in[16];
  const float* g2 = (const float*)d_in[17];
  const float* b2 = (const float*)d_in[18];
  const float* m2 = (const float*)d_in[19];
  const float* v2 = (const float*)d_in[20];
  const float* ab = (const float*)d_in[21];
  float* out = (float*)d_out;

  char* ws = (char*)d_ws;
  uint16_t* qt  = (uint16_t*)(ws);                 // 8 MiB  [bh][32][1024]
  uint16_t* kwsp= (uint16_t*)(ws + (8ull << 20));  // 8 MiB  [bh][1024][32]
  uint16_t* vt  = (uint16_t*)(ws + (16ull << 20)); // 16 MiB [bh][64][1024]
  float*    ows = (float*)(ws + (32ull << 20));    // 32 MiB
  float*    x1  = (float*)(ws + (64ull << 20));    // 16 MiB
  uint16_t* h1  = (uint16_t*)(ws);                 // reuse qt/kws region (dead after K2)
  float* wqkvt = (float*)(ws + (80ull << 20));
  float* shq   = wqkvt + 65536;
  float* wpt   = shq + 512;
  float* shp   = wpt + 32768;
  float* w1t   = shp + 128;
  float* sh1   = w1t + 32768;
  float* w2t   = sh1 + 256;
  float* sh2   = w2t + 32768;

  k0_fold<<<644, 256, 0, stream>>>(Wq, gq, bq, mq, vq, Wp, gp, bp, mp, vp,
                                   W1, g1, b1, m1, v1, W2, g2, b2, m2, v2,
                                   wqkvt, shq, wpt, shp, w1t, sh1, w2t, sh2);
  k1_qkv<<<1024, 256, 0, stream>>>(x, wqkvt, shq, qt, kwsp, vt);
  k2_attn<<<2048, 256, 0, stream>>>(qt, kwsp, vt, ab, ows);
  k3_proj<<<1024, 256, 0, stream>>>(ows, x, wpt, shp, x1);
  k4_f1<<<1024, 256, 0, stream>>>(x1, w1t, sh1, h1);
  k5_f2<<<1024, 256, 0, stream>>>(h1, x1, w2t, sh2, out);
  (void)in_sizes; (void)n_in; (void)out_size; (void)ws_size;
}